// Round 15
// baseline (906.710 us; speedup 1.0000x reference)
//
#include <hip/hip_runtime.h>

// 3-layer LSTM encoder. B=512, T=512, F=8, HID=128, EMB=64.
// R15: role-split waves. 96 blocks (3 stages x 32 tiles) x 1024 thr = 16 waves:
//  odd waves  = x-waves: pacc[par^1] = bias + x(t+1)@Wih  (MFMA, 16/step)
//  even waves = h-waves: acc = ds_read(pacc[par]); acc += h@Whh; pointwise; h
// Each wave carries ONE 64-reg weight set (role-shared register file) ->
// ~112 VGPR/wave -> 4 waves/SIMD; h-wave trans overlaps x-wave MFMAs.
// One lgkmcnt-only barrier per step. Chunk flag pipeline as R10.
// LDS: h_lds 8704B + pacc 64KB. ws: [O1 67MB][O2 67MB][flags]

#define DEVI __device__ __forceinline__

typedef _Float16 h8 __attribute__((ext_vector_type(8)));
typedef float f4 __attribute__((ext_vector_type(4)));

static constexpr int T_ = 512, TC_ = 16, NC_ = T_ / TC_;

DEVI float rcpf_(float x) { return __builtin_amdgcn_rcpf(x); }
DEVI float exp2f_(float x) { return __builtin_amdgcn_exp2f(x); }

DEVI h8 cvt8(const float* p) {
    const float4 a = *reinterpret_cast<const float4*>(p);
    const float4 b = *reinterpret_cast<const float4*>(p + 4);
    return h8{(_Float16)a.x, (_Float16)a.y, (_Float16)a.z, (_Float16)a.w,
              (_Float16)b.x, (_Float16)b.y, (_Float16)b.z, (_Float16)b.w};
}

DEVI void lds_barrier() {
    asm volatile("s_waitcnt lgkmcnt(0)\n\ts_barrier" ::: "memory");
}

// LAYER=1: H=128, x from f32 input (K=8 zero-padded)
// LAYER=2: H=128, x from O1, writes O2
// LAYER=3: H=64,  x from O2, writes out at t=511
template <int LAYER>
DEVI void stage(int tile, char* smem, const float* x, const _Float16* Oin,
                _Float16* Oout, const float* Wih, const float* Whh,
                const float* bih, const float* bhh, float* out,
                int* flag_in, int* flag_out) {
    constexpr int H = (LAYER == 3) ? 64 : 128;
    constexpr int KT_H = H / 32;               // h K-tiles (4 or 2)
    constexpr int KT_X = (LAYER == 1) ? 1 : 4; // x K-tiles
    constexpr int HP = H + 8;                  // padded h row (f16)
    constexpr int NJG = H / 16;                // j-groups (8 or 4)

    const int tid = threadIdx.x, lane = tid & 63, wv = tid >> 6;
    const int lr = lane & 15, lk = lane >> 4;
    const int b0 = tile * 16;
    const int isx = wv & 1;           // odd wave = x-projection wave
    const int jg = wv >> 1;           // j-group: paired h/x waves share it
    const bool act = (jg < NJG);
    const int jcol = jg * 16 + lr;

    _Float16 (*h_lds)[16][HP] = (_Float16 (*)[16][HP])smem;
    float* pacc = (float*)(smem + 8704);   // [2][8][4][64 lanes][4 f32] = 64KB

    // ---- role-shared register file ----
    h8 wreg[16];                      // h-wave: Whh frags; x-wave: Wih frags
    f4 acc[4];
    h8 tmp8[4];                       // h-wave: h A-frags; x-wave: x A-frags
    float state[4] = {0.f, 0.f, 0.f, 0.f};  // h-wave: c; x-wave: bias

    if (act) {
        if (!isx) {
#pragma unroll
            for (int kt = 0; kt < KT_H; kt++)
#pragma unroll
                for (int q = 0; q < 4; q++)
                    wreg[kt * 4 + q] = cvt8(Whh + (size_t)(q * H + jcol) * H + kt * 32 + lk * 8);
        } else {
#pragma unroll
            for (int q = 0; q < 4; q++) {
                if constexpr (LAYER == 1) {
                    wreg[q] = (lk == 0) ? cvt8(Wih + (size_t)(q * H + jcol) * 8) : h8{};
                } else {
#pragma unroll
                    for (int kt = 0; kt < KT_X; kt++)
                        wreg[q * KT_X + kt] = cvt8(Wih + (size_t)(q * H + jcol) * 128 + kt * 32 + lk * 8);
                }
                state[q] = bih[q * H + jcol] + bhh[q * H + jcol];
            }
        }
    }

    for (int i = tid; i < 2 * 16 * HP; i += 1024) ((_Float16*)smem)[i] = (_Float16)0;
    __syncthreads();

    // x-wave: load x(t) A-frags into tmp8
    auto load_x = [&](int t) {
        if constexpr (LAYER == 1) {
            tmp8[0] = (lk == 0) ? cvt8(x + ((size_t)(b0 + lr) * T_ + t) * 8) : h8{};
        } else {
#pragma unroll
            for (int kt = 0; kt < KT_X; kt++)
                tmp8[kt] = *reinterpret_cast<const h8*>(
                    Oin + ((size_t)(b0 + lr) * T_ + t) * 128 + kt * 32 + lk * 8);
        }
    };
    // x-wave: pacc[par] = bias + tmp8 @ Wih^T
    auto xproj = [&](int par) {
#pragma unroll
        for (int q = 0; q < 4; q++) acc[q] = f4{state[q], state[q], state[q], state[q]};
#pragma unroll
        for (int kt = 0; kt < KT_X; kt++)
#pragma unroll
            for (int q = 0; q < 4; q++)
                acc[q] = __builtin_amdgcn_mfma_f32_16x16x32_f16(tmp8[kt], wreg[q * KT_X + kt],
                                                                acc[q], 0, 0, 0);
#pragma unroll
        for (int q = 0; q < 4; q++)
            *reinterpret_cast<f4*>(pacc + ((size_t)((par * 8 + jg) * 4 + q)) * 256 + lane * 4) = acc[q];
    };

    // one step; PAR is a literal (0/1)
#define STEP(TT_EXPR, PAR)                                                                \
    {                                                                                     \
        const int tt = (TT_EXPR);                                                         \
        const int t = t0 + tt;                                                            \
        if (act) {                                                                        \
            if (!isx) {                                                                   \
                _Pragma("unroll")                                                         \
                for (int q = 0; q < 4; q++)                                               \
                    acc[q] = *reinterpret_cast<const f4*>(                                \
                        pacc + ((size_t)(((PAR) * 8 + jg) * 4 + q)) * 256 + lane * 4);    \
                _Pragma("unroll")                                                         \
                for (int kt = 0; kt < KT_H; kt++)                                         \
                    tmp8[kt] = *reinterpret_cast<const h8*>(&h_lds[PAR][lr][kt * 32 + lk * 8]); \
                _Pragma("unroll")                                                         \
                for (int kt = 0; kt < KT_H; kt++)                                         \
                    _Pragma("unroll")                                                     \
                    for (int q = 0; q < 4; q++)                                           \
                        acc[q] = __builtin_amdgcn_mfma_f32_16x16x32_f16(tmp8[kt],         \
                                     wreg[kt * 4 + q], acc[q], 0, 0, 0);                  \
                float e0[4], e1[4], e2[4], e3[4];                                         \
                _Pragma("unroll")                                                         \
                for (int i = 0; i < 4; i++) {                                             \
                    e0[i] = exp2f_(acc[0][i] * -1.44269504f);                             \
                    e1[i] = exp2f_(acc[1][i] * -1.44269504f);                             \
                    e2[i] = exp2f_(acc[2][i] * -2.88539008f);                             \
                    e3[i] = exp2f_(acc[3][i] * -1.44269504f);                             \
                }                                                                         \
                _Pragma("unroll")                                                         \
                for (int i = 0; i < 4; i++) {                                             \
                    const float gi = rcpf_(1.f + e0[i]);                                  \
                    const float gf = rcpf_(1.f + e1[i]);                                  \
                    const float gg = 2.f * rcpf_(1.f + e2[i]) - 1.f;                      \
                    const float go = rcpf_(1.f + e3[i]);                                  \
                    state[i] = gf * state[i] + gi * gg;                                   \
                    const float th = 2.f * rcpf_(1.f + exp2f_(state[i] * -2.88539008f)) - 1.f; \
                    const float h = go * th;                                              \
                    const int row = lk * 4 + i;                                           \
                    h_lds[(PAR) ^ 1][row][jcol] = (_Float16)h;                            \
                    if constexpr (LAYER < 3) {                                            \
                        Oout[((size_t)(b0 + row) * T_ + t) * 128 + jcol] = (_Float16)h;   \
                    } else {                                                              \
                        if (t == T_ - 1) out[(size_t)(b0 + row) * 64 + jcol] = h;         \
                    }                                                                     \
                }                                                                         \
            } else {                                                                      \
                if (tt < TC_ - 1) xproj((PAR) ^ 1);      /* pacc for step tt+1 */         \
                if (tt < TC_ - 2) load_x(t + 2);         /* consumed next step */         \
            }                                                                             \
        }                                                                                 \
    }

    for (int ch = 0; ch < NC_; ch++) {
        // ---- consumer: wait for input chunk ch ----
        if constexpr (LAYER > 1) {
            if (tid == 0) {
                while (__hip_atomic_load(flag_in, __ATOMIC_RELAXED,
                                         __HIP_MEMORY_SCOPE_AGENT) < ch + 1)
                    __builtin_amdgcn_s_sleep(2);
                __threadfence();   // agent acquire
            }
        }
        __syncthreads();
        const int t0 = ch * TC_;

        // chunk-head mini-phase: x-waves fill pacc[0] for step 0, preload x(t0+1)
        if (act && isx) {
            load_x(t0);
            xproj(0);
            load_x(t0 + 1);
        }
        lds_barrier();

        for (int tb = 0; tb < TC_ / 2; tb++) {
            STEP(2 * tb, 0)
            lds_barrier();
            STEP(2 * tb + 1, 1)
            lds_barrier();
        }

        // ---- producer: publish chunk ch ----
        if constexpr (LAYER < 3) {
            asm volatile("s_waitcnt vmcnt(0)" ::: "memory");
            __syncthreads();
            if (tid == 0) {
                __threadfence();   // agent release
                __hip_atomic_store(flag_out, ch + 1, __ATOMIC_RELAXED,
                                   __HIP_MEMORY_SCOPE_AGENT);
            }
        }
    }
#undef STEP
}

__global__ __launch_bounds__(1024)
void mega_k(const float* __restrict__ x,
            const float* __restrict__ Wih1, const float* __restrict__ Whh1,
            const float* __restrict__ bih1, const float* __restrict__ bhh1,
            const float* __restrict__ Wih2, const float* __restrict__ Whh2,
            const float* __restrict__ bih2, const float* __restrict__ bhh2,
            const float* __restrict__ Wih3, const float* __restrict__ Whh3,
            const float* __restrict__ bih3, const float* __restrict__ bhh3,
            _Float16* __restrict__ O1, _Float16* __restrict__ O2,
            float* __restrict__ out, int* __restrict__ flags) {
    extern __shared__ char smem[];
    const int bid = blockIdx.x;
    if (bid < 32) {
        stage<1>(bid, smem, x, nullptr, O1, Wih1, Whh1, bih1, bhh1, nullptr,
                 nullptr, flags + bid);
    } else if (bid < 64) {
        stage<2>(bid - 32, smem, nullptr, O1, O2, Wih2, Whh2, bih2, bhh2, nullptr,
                 flags + (bid - 32), flags + 32 + (bid - 32));
    } else {
        stage<3>(bid - 64, smem, nullptr, O2, nullptr, Wih3, Whh3, bih3, bhh3, out,
                 flags + 32 + (bid - 64), nullptr);
    }
}

__global__ void zero_flags_k(int* flags) {
    if (threadIdx.x < 64)
        __hip_atomic_store(flags + threadIdx.x, 0, __ATOMIC_RELAXED,
                           __HIP_MEMORY_SCOPE_AGENT);
}

extern "C" void kernel_launch(void* const* d_in, const int* in_sizes, int n_in,
                              void* d_out, int out_size, void* d_ws, size_t ws_size,
                              hipStream_t stream) {
    const float* x = (const float*)d_in[0];
    float* out = (float*)d_out;

    char* ws = (char*)d_ws;
    _Float16* O1 = (_Float16*)ws;                         // 67,108,864 B
    _Float16* O2 = (_Float16*)(ws + (size_t)67108864);    // 67,108,864 B
    int* flags   = (int*)(ws + (size_t)134217728);        // 256 B
    (void)ws_size; (void)in_sizes; (void)n_in; (void)out_size;

    // LDS: h_lds 8704 B + pacc 65536 B = 74240 B
    zero_flags_k<<<1, 64, 0, stream>>>(flags);
    mega_k<<<96, 1024, 74240, stream>>>(
        x,
        (const float*)d_in[1], (const float*)d_in[2], (const float*)d_in[3], (const float*)d_in[4],
        (const float*)d_in[5], (const float*)d_in[6], (const float*)d_in[7], (const float*)d_in[8],
        (const float*)d_in[9], (const float*)d_in[10], (const float*)d_in[11], (const float*)d_in[12],
        O1, O2, out, flags);
}

// Round 16
// 711.382 us; speedup vs baseline: 1.2746x; 1.2746x over previous
//
#include <hip/hip_runtime.h>

// 3-layer LSTM encoder. B=512, T=512, F=8, HID=128, EMB=64.
// R16: 4-stage pipelined mega-kernel, 128 blocks x 512 thr:
//   L1 (0-31):   recurrence, fused K=8 x-proj, writes O1 ring (2 slots/tile)
//   P2 (32-63):  GEMM xp2 = bias2 + O1@Wih2^T -> xp ring, in L2's C-frag layout
//   L2 (64-95):  recurrence, acc init = xp loads (NO x-MFMAs), writes O2 full
//   L3 (96-127): recurrence (x from O2, internal x-MFMA), writes out at t=511
// All flag stores preceded by __threadfence (incl. consumption flags - R9 fix).
// ws: [O1 ring 4MB][xp ring 16MB][O2 67MB][flags]

#define DEVI __device__ __forceinline__

typedef _Float16 h4 __attribute__((ext_vector_type(4)));
typedef _Float16 h8 __attribute__((ext_vector_type(8)));
typedef float f4 __attribute__((ext_vector_type(4)));

static constexpr int T_ = 512, TC_ = 16, NC_ = T_ / TC_, RC_ = 2;

DEVI float rcpf_(float x) { return __builtin_amdgcn_rcpf(x); }
DEVI float exp2f_(float x) { return __builtin_amdgcn_exp2f(x); }

DEVI h8 cvt8(const float* p) {
    const float4 a = *reinterpret_cast<const float4*>(p);
    const float4 b = *reinterpret_cast<const float4*>(p + 4);
    return h8{(_Float16)a.x, (_Float16)a.y, (_Float16)a.z, (_Float16)a.w,
              (_Float16)b.x, (_Float16)b.y, (_Float16)b.z, (_Float16)b.w};
}

DEVI void lds_barrier() {
    asm volatile("s_waitcnt lgkmcnt(0)\n\ts_barrier" ::: "memory");
}
DEVI int ld_flag(int* f) {
    return __hip_atomic_load(f, __ATOMIC_RELAXED, __HIP_MEMORY_SCOPE_AGENT);
}
DEVI void st_flag(int* f, int v) {
    __hip_atomic_store(f, v, __ATOMIC_RELAXED, __HIP_MEMORY_SCOPE_AGENT);
}

// shared pointwise: acc -> c,h  (i,f,g,o sigmoid/tanh; batched exp2 then rcp)
#define POINTWISE_PROLOG(ACC)                                                   \
    float e0[4], e1[4], e2[4], e3[4];                                           \
    _Pragma("unroll") for (int i = 0; i < 4; i++) {                             \
        e0[i] = exp2f_(ACC[0][i] * -1.44269504f);                               \
        e1[i] = exp2f_(ACC[1][i] * -1.44269504f);                               \
        e2[i] = exp2f_(ACC[2][i] * -2.88539008f);                               \
        e3[i] = exp2f_(ACC[3][i] * -1.44269504f); }

#define POINTWISE_CELL(i, C, HVAR)                                              \
    const float gi = rcpf_(1.f + e0[i]), gf = rcpf_(1.f + e1[i]);               \
    const float gg = 2.f * rcpf_(1.f + e2[i]) - 1.f, go = rcpf_(1.f + e3[i]);   \
    C[i] = gf * C[i] + gi * gg;                                                 \
    const float HVAR = go * (2.f * rcpf_(1.f + exp2f_(C[i] * -2.88539008f)) - 1.f);

// ---------------- stage L1 ----------------
DEVI void stage_L1(int tile, char* smem, const float* x, const float* Wih,
                   const float* Whh, const float* bih, const float* bhh,
                   _Float16* o1, int* c1, int* p1) {
    constexpr int H = 128, KT_H = 4, HP = H + 8;
    const int tid = threadIdx.x, lane = tid & 63, wv = tid >> 6;
    const int lr = lane & 15, lk = lane >> 4;
    const int b0 = tile * 16;
    const int jcol = wv * 16 + lr;
    _Float16 (*h_lds)[16][HP] = (_Float16 (*)[16][HP])smem;

    h8 wbh[4][KT_H], wbx[4];
    float bias[4];
#pragma unroll
    for (int q = 0; q < 4; q++) {
#pragma unroll
        for (int kt = 0; kt < KT_H; kt++)
            wbh[q][kt] = cvt8(Whh + (size_t)(q * H + jcol) * H + kt * 32 + lk * 8);
        wbx[q] = (lk == 0) ? cvt8(Wih + (size_t)(q * H + jcol) * 8) : h8{};
        bias[q] = bih[q * H + jcol] + bhh[q * H + jcol];
    }
    float c[4] = {0.f, 0.f, 0.f, 0.f};
    for (int i = tid; i < 2 * 16 * HP; i += 512) ((_Float16*)smem)[i] = (_Float16)0;
    __syncthreads();

    auto load_x = [&](int t, h8& xa) {
        xa = (lk == 0) ? cvt8(x + ((size_t)(b0 + lr) * T_ + t) * 8) : h8{};
    };
    h8 xa, xb;

#define L1_STEP(TT, CUR, XS) {                                                  \
    const int tt = (TT);                                                        \
    h8 ha[KT_H];                                                                \
    _Pragma("unroll") for (int kt = 0; kt < KT_H; kt++)                         \
        ha[kt] = *reinterpret_cast<const h8*>(&h_lds[CUR][lr][kt * 32 + lk * 8]); \
    f4 acc[4];                                                                  \
    _Pragma("unroll") for (int q = 0; q < 4; q++)                               \
        acc[q] = f4{bias[q], bias[q], bias[q], bias[q]};                        \
    _Pragma("unroll") for (int q = 0; q < 4; q++)                               \
        acc[q] = __builtin_amdgcn_mfma_f32_16x16x32_f16(XS, wbx[q], acc[q], 0, 0, 0); \
    _Pragma("unroll") for (int kt = 0; kt < KT_H; kt++)                         \
        _Pragma("unroll") for (int q = 0; q < 4; q++)                           \
            acc[q] = __builtin_amdgcn_mfma_f32_16x16x32_f16(ha[kt], wbh[q][kt], acc[q], 0, 0, 0); \
    if (tt + 2 < TC_) load_x(t0 + tt + 2, XS);                                  \
    POINTWISE_PROLOG(acc)                                                       \
    _Pragma("unroll") for (int i = 0; i < 4; i++) {                             \
        POINTWISE_CELL(i, c, h)                                                 \
        const int row = lk * 4 + i;                                             \
        h_lds[(CUR) ^ 1][row][jcol] = (_Float16)h;                              \
        o1[(((size_t)(tile * RC_ + slot) * TC_ + tt) * 16 + row) * 128 + jcol] = (_Float16)h; } }

    for (int ch = 0; ch < NC_; ch++) {
        const int slot = ch & (RC_ - 1);
        if (tid == 0) {  // wait: P2 consumed chunk ch-2 of O1
            while (ld_flag(c1) < ch - (RC_ - 1)) __builtin_amdgcn_s_sleep(8);
        }
        __syncthreads();
        const int t0 = ch * TC_;
        load_x(t0, xa); load_x(t0 + 1, xb);
        for (int tb = 0; tb < TC_ / 2; tb++) {
            L1_STEP(2 * tb, 0, xa) lds_barrier();
            L1_STEP(2 * tb + 1, 1, xb) lds_barrier();
        }
        asm volatile("s_waitcnt vmcnt(0)" ::: "memory");
        __syncthreads();
        if (tid == 0) { __threadfence(); st_flag(p1, ch + 1); }
    }
#undef L1_STEP
}

// ---------------- stage P2 (xp GEMM) ----------------
DEVI void stage_P2(int tile, const _Float16* o1, _Float16* xp, const float* Wih,
                   const float* bih, const float* bhh,
                   int* p1, int* c1, int* cx, int* px) {
    constexpr int H = 128;
    const int tid = threadIdx.x, lane = tid & 63, wv = tid >> 6;
    const int lr = lane & 15, lk = lane >> 4;
    const int jcol = wv * 16 + lr;

    h8 wbx[4][4];
    float pbias[4];
#pragma unroll
    for (int q = 0; q < 4; q++) {
#pragma unroll
        for (int kt = 0; kt < 4; kt++)
            wbx[q][kt] = cvt8(Wih + (size_t)(q * H + jcol) * 128 + kt * 32 + lk * 8);
        pbias[q] = bih[q * H + jcol] + bhh[q * H + jcol];
    }

    for (int ch = 0; ch < NC_; ch++) {
        const int slot = ch & (RC_ - 1);
        if (tid == 0) {
            while (ld_flag(p1) < ch + 1) __builtin_amdgcn_s_sleep(8);            // O1 ready
            while (ld_flag(cx) < ch - (RC_ - 1)) __builtin_amdgcn_s_sleep(8);    // xp slot free
            __threadfence();   // acquire before reading O1 slot
        }
        __syncthreads();
        const size_t ib = (size_t)(tile * RC_ + slot) * TC_ * 2048;   // o1 f16 base
        const size_t ob = (size_t)(tile * RC_ + slot) * TC_ * 8192;   // xp f16 base
#pragma unroll 4
        for (int t = 0; t < TC_; t++) {
            h8 af[4];
#pragma unroll
            for (int kt = 0; kt < 4; kt++)
                af[kt] = *reinterpret_cast<const h8*>(o1 + ib + (size_t)t * 2048 + lr * 128 + kt * 32 + lk * 8);
            f4 acc[4];
#pragma unroll
            for (int q = 0; q < 4; q++) acc[q] = f4{pbias[q], pbias[q], pbias[q], pbias[q]};
#pragma unroll
            for (int kt = 0; kt < 4; kt++)
#pragma unroll
                for (int q = 0; q < 4; q++)
                    acc[q] = __builtin_amdgcn_mfma_f32_16x16x32_f16(af[kt], wbx[q][kt], acc[q], 0, 0, 0);
#pragma unroll
            for (int q = 0; q < 4; q++) {
                const h4 o = h4{(_Float16)acc[q][0], (_Float16)acc[q][1],
                                (_Float16)acc[q][2], (_Float16)acc[q][3]};
                *reinterpret_cast<h4*>(xp + ob + (size_t)t * 8192 + (wv * 4 + q) * 256 + lane * 4) = o;
            }
        }
        asm volatile("s_waitcnt vmcnt(0)" ::: "memory");
        __syncthreads();
        if (tid == 0) { __threadfence(); st_flag(px, ch + 1); st_flag(c1, ch + 1); }
    }
}

// ---------------- stage L2 ----------------
DEVI void stage_L2(int tile, char* smem, const _Float16* xp, _Float16* O2,
                   const float* Whh, int* px, int* cx, int* p2) {
    constexpr int H = 128, KT_H = 4, HP = H + 8;
    const int tid = threadIdx.x, lane = tid & 63, wv = tid >> 6;
    const int lr = lane & 15, lk = lane >> 4;
    const int b0 = tile * 16;
    const int jcol = wv * 16 + lr;
    _Float16 (*h_lds)[16][HP] = (_Float16 (*)[16][HP])smem;

    h8 wbh[4][KT_H];
#pragma unroll
    for (int q = 0; q < 4; q++)
#pragma unroll
        for (int kt = 0; kt < KT_H; kt++)
            wbh[q][kt] = cvt8(Whh + (size_t)(q * H + jcol) * H + kt * 32 + lk * 8);

    float c[4] = {0.f, 0.f, 0.f, 0.f};
    for (int i = tid; i < 2 * 16 * HP; i += 512) ((_Float16*)smem)[i] = (_Float16)0;
    __syncthreads();

    h4 xqa[4], xqb[4];   // parity xp prefetch (even/odd tt)

#define LOAD_XP(SLOT, TTL, DST) {                                               \
    const size_t base = ((size_t)(tile * RC_ + (SLOT)) * TC_ + (TTL)) * 8192 + wv * 1024 + lane * 4; \
    _Pragma("unroll") for (int q = 0; q < 4; q++)                               \
        DST[q] = *reinterpret_cast<const h4*>(xp + base + q * 256); }

#define L2_STEP(TT, CUR, XQ) {                                                  \
    const int tt = (TT); const int t = t0 + tt;                                 \
    h8 ha[KT_H];                                                                \
    _Pragma("unroll") for (int kt = 0; kt < KT_H; kt++)                         \
        ha[kt] = *reinterpret_cast<const h8*>(&h_lds[CUR][lr][kt * 32 + lk * 8]); \
    f4 acc[4];                                                                  \
    _Pragma("unroll") for (int q = 0; q < 4; q++)                               \
        acc[q] = f4{(float)XQ[q][0], (float)XQ[q][1], (float)XQ[q][2], (float)XQ[q][3]}; \
    _Pragma("unroll") for (int kt = 0; kt < KT_H; kt++)                         \
        _Pragma("unroll") for (int q = 0; q < 4; q++)                           \
            acc[q] = __builtin_amdgcn_mfma_f32_16x16x32_f16(ha[kt], wbh[q][kt], acc[q], 0, 0, 0); \
    if (tt + 2 < TC_) LOAD_XP(slot, tt + 2, XQ)                                 \
    POINTWISE_PROLOG(acc)                                                       \
    _Pragma("unroll") for (int i = 0; i < 4; i++) {                             \
        POINTWISE_CELL(i, c, h)                                                 \
        const int row = lk * 4 + i;                                             \
        h_lds[(CUR) ^ 1][row][jcol] = (_Float16)h;                              \
        O2[((size_t)(b0 + row) * T_ + t) * 128 + jcol] = (_Float16)h; } }

    for (int ch = 0; ch < NC_; ch++) {
        const int slot = ch & (RC_ - 1);
        if (tid == 0) {
            while (ld_flag(px) < ch + 1) __builtin_amdgcn_s_sleep(8);
            __threadfence();   // acquire before reading xp slot
        }
        __syncthreads();
        const int t0 = ch * TC_;
        LOAD_XP(slot, 0, xqa)
        LOAD_XP(slot, 1, xqb)
        for (int tb = 0; tb < TC_ / 2; tb++) {
            L2_STEP(2 * tb, 0, xqa) lds_barrier();
            L2_STEP(2 * tb + 1, 1, xqb) lds_barrier();
        }
        asm volatile("s_waitcnt vmcnt(0)" ::: "memory");
        __syncthreads();
        if (tid == 0) { __threadfence(); st_flag(p2, ch + 1); st_flag(cx, ch + 1); }
    }
#undef L2_STEP
#undef LOAD_XP
}

// ---------------- stage L3 ----------------
DEVI void stage_L3(int tile, char* smem, const _Float16* O2, const float* Wih,
                   const float* Whh, const float* bih, const float* bhh,
                   float* out, int* p2) {
    constexpr int H = 64, KT_H = 2, KT_X = 4, HP = H + 8;
    const int tid = threadIdx.x, lane = tid & 63, wv = tid >> 6;
    const int lr = lane & 15, lk = lane >> 4;
    const int b0 = tile * 16;
    const bool act = (wv < 4);
    const int jcol = (wv & 3) * 16 + lr;
    _Float16 (*h_lds)[16][HP] = (_Float16 (*)[16][HP])smem;

    h8 wbh[4][KT_H], wbx[4][KT_X];
    float bias[4];
    if (act) {
#pragma unroll
        for (int q = 0; q < 4; q++) {
#pragma unroll
            for (int kt = 0; kt < KT_H; kt++)
                wbh[q][kt] = cvt8(Whh + (size_t)(q * H + jcol) * H + kt * 32 + lk * 8);
#pragma unroll
            for (int kt = 0; kt < KT_X; kt++)
                wbx[q][kt] = cvt8(Wih + (size_t)(q * H + jcol) * 128 + kt * 32 + lk * 8);
            bias[q] = bih[q * H + jcol] + bhh[q * H + jcol];
        }
    }
    float c[4] = {0.f, 0.f, 0.f, 0.f};
    for (int i = tid; i < 2 * 16 * HP; i += 512) ((_Float16*)smem)[i] = (_Float16)0;
    __syncthreads();

    auto load_x = [&](int t, h8* xa) {
#pragma unroll
        for (int kt = 0; kt < KT_X; kt++)
            xa[kt] = *reinterpret_cast<const h8*>(
                O2 + ((size_t)(b0 + lr) * T_ + t) * 128 + kt * 32 + lk * 8);
    };
    h8 xa[KT_X], xb[KT_X];

#define L3_STEP(TT, CUR, XS) {                                                  \
    const int tt = (TT); const int t = t0 + tt;                                 \
    if (act) {                                                                  \
        h8 ha[KT_H];                                                            \
        _Pragma("unroll") for (int kt = 0; kt < KT_H; kt++)                     \
            ha[kt] = *reinterpret_cast<const h8*>(&h_lds[CUR][lr][kt * 32 + lk * 8]); \
        f4 acc[4];                                                              \
        _Pragma("unroll") for (int q = 0; q < 4; q++)                           \
            acc[q] = f4{bias[q], bias[q], bias[q], bias[q]};                    \
        _Pragma("unroll") for (int kt = 0; kt < KT_X; kt++)                     \
            _Pragma("unroll") for (int q = 0; q < 4; q++)                       \
                acc[q] = __builtin_amdgcn_mfma_f32_16x16x32_f16(XS[kt], wbx[q][kt], acc[q], 0, 0, 0); \
        _Pragma("unroll") for (int kt = 0; kt < KT_H; kt++)                     \
            _Pragma("unroll") for (int q = 0; q < 4; q++)                       \
                acc[q] = __builtin_amdgcn_mfma_f32_16x16x32_f16(ha[kt], wbh[q][kt], acc[q], 0, 0, 0); \
        if (tt + 2 < TC_) load_x(t + 2, XS);                                    \
        POINTWISE_PROLOG(acc)                                                   \
        _Pragma("unroll") for (int i = 0; i < 4; i++) {                         \
            POINTWISE_CELL(i, c, h)                                             \
            const int row = lk * 4 + i;                                         \
            h_lds[(CUR) ^ 1][row][jcol] = (_Float16)h;                          \
            if (t == T_ - 1) out[(size_t)(b0 + row) * 64 + jcol] = h; } } }

    for (int ch = 0; ch < NC_; ch++) {
        if (tid == 0) {
            while (ld_flag(p2) < ch + 1) __builtin_amdgcn_s_sleep(8);
            __threadfence();   // acquire before reading O2 chunk
        }
        __syncthreads();
        const int t0 = ch * TC_;
        if (act) { load_x(t0, xa); load_x(t0 + 1, xb); }
        for (int tb = 0; tb < TC_ / 2; tb++) {
            L3_STEP(2 * tb, 0, xa) lds_barrier();
            L3_STEP(2 * tb + 1, 1, xb) lds_barrier();
        }
    }
#undef L3_STEP
}

__global__ __launch_bounds__(512, 1)
void mega_k(const float* __restrict__ x,
            const float* __restrict__ Wih1, const float* __restrict__ Whh1,
            const float* __restrict__ bih1, const float* __restrict__ bhh1,
            const float* __restrict__ Wih2, const float* __restrict__ Whh2,
            const float* __restrict__ bih2, const float* __restrict__ bhh2,
            const float* __restrict__ Wih3, const float* __restrict__ Whh3,
            const float* __restrict__ bih3, const float* __restrict__ bhh3,
            _Float16* __restrict__ o1ring, _Float16* __restrict__ xpring,
            _Float16* __restrict__ O2, float* __restrict__ out,
            int* __restrict__ flags) {
    extern __shared__ char smem[];
    const int bid = blockIdx.x;
    int* p1 = flags;          // L1 chunk done        [32]
    int* c1 = flags + 32;     // P2 consumed O1       [32]
    int* px = flags + 64;     // P2 xp slot done      [32]
    int* cx = flags + 96;     // L2 consumed xp       [32]
    int* p2 = flags + 128;    // L2 chunk done        [32]
    if (bid < 32) {
        stage_L1(bid, smem, x, Wih1, Whh1, bih1, bhh1, o1ring, c1 + bid, p1 + bid);
    } else if (bid < 64) {
        const int t = bid - 32;
        stage_P2(t, o1ring, xpring, Wih2, bih2, bhh2, p1 + t, c1 + t, cx + t, px + t);
    } else if (bid < 96) {
        const int t = bid - 64;
        stage_L2(t, smem, xpring, O2, Whh2, px + t, cx + t, p2 + t);
    } else {
        const int t = bid - 96;
        stage_L3(t, smem, O2, Wih3, Whh3, bih3, bhh3, out, p2 + t);
    }
}

__global__ void zero_flags_k(int* flags) {
    if (threadIdx.x < 160)
        __hip_atomic_store(flags + threadIdx.x, 0, __ATOMIC_RELAXED,
                           __HIP_MEMORY_SCOPE_AGENT);
}

extern "C" void kernel_launch(void* const* d_in, const int* in_sizes, int n_in,
                              void* d_out, int out_size, void* d_ws, size_t ws_size,
                              hipStream_t stream) {
    const float* x = (const float*)d_in[0];
    float* out = (float*)d_out;

    char* ws = (char*)d_ws;
    _Float16* o1ring = (_Float16*)ws;                          // 4,194,304 B
    _Float16* xpring = (_Float16*)(ws + (size_t)4194304);      // 16,777,216 B
    _Float16* O2     = (_Float16*)(ws + (size_t)20971520);     // 67,108,864 B
    int* flags       = (int*)(ws + (size_t)88080384);          // 640 B
    (void)ws_size; (void)in_sizes; (void)n_in; (void)out_size;

    zero_flags_k<<<1, 192, 0, stream>>>(flags);
    mega_k<<<128, 512, 8704, stream>>>(
        x,
        (const float*)d_in[1], (const float*)d_in[2], (const float*)d_in[3], (const float*)d_in[4],
        (const float*)d_in[5], (const float*)d_in[6], (const float*)d_in[7], (const float*)d_in[8],
        (const float*)d_in[9], (const float*)d_in[10], (const float*)d_in[11], (const float*)d_in[12],
        o1ring, xpring, O2, out, flags);
}